// Round 5
// baseline (145.915 us; speedup 1.0000x reference)
//
#include <hip/hip_runtime.h>
#include <hip/hip_bf16.h>

typedef short v8s __attribute__((ext_vector_type(8)));
typedef float v16f __attribute__((ext_vector_type(16)));
typedef unsigned v2u __attribute__((ext_vector_type(2)));

#define F_ 128
#define K_ 512
#define M_ 65536
#define CH_SH 17408   // shorts per chunk table: Cb' 9216 (64c x 144f) + CT' 8192 (64c x 128f)
#define CB_OFF 9216

typedef __attribute__((address_space(1))) const char gch;
typedef __attribute__((address_space(3))) char lch;

__device__ __forceinline__ short f2bf(float f) {
    union { float f; unsigned u; } v; v.f = f;
    unsigned u = v.u;
    u = (u + 0x7FFFu + ((u >> 16) & 1u)) >> 16;  // RNE
    return (short)u;
}
__device__ __forceinline__ float bf2f(short s) {
    union { float f; unsigned u; } v;
    v.u = ((unsigned)(unsigned short)s) << 16;
    return v.f;
}

#if __has_builtin(__builtin_amdgcn_permlane32_swap)
#define HAVE_PLS 1
#endif

// (a,b) -> (a.lo||b.lo, a.hi||b.hi): the half-wave exchange for C->A layout.
__device__ __forceinline__ void pswap(unsigned &a, unsigned &b, int lane) {
#ifdef HAVE_PLS
    v2u r = __builtin_amdgcn_permlane32_swap(a, b, false, false);
    a = (unsigned)r.x; b = (unsigned)r.y;
#else
    unsigned sa = (unsigned)__shfl_xor((int)a, 32);
    unsigned sb = (unsigned)__shfl_xor((int)b, 32);
    if (lane & 32) a = sb; else b = sa;
#endif
}

// Build combined per-chunk tables in fragment-granule order (verified R4).
__global__ void prep_kernel(const float* __restrict__ centers, short* __restrict__ G) {
    const int c = blockIdx.x;     // 512 clusters
    const int f = threadIdx.x;    // 128 features
    const int ch = c >> 6, c64 = c & 63;
    const size_t base = (size_t)ch * CH_SH;
    float v = centers[c * F_ + f];
    short b = f2bf(v);
    float vb = bf2f(b);
    { const int ks = f >> 4, h = (f >> 3) & 1, j = f & 7;
      G[base + (size_t)((ks * 2 + h) * 64 + c64) * 8 + j] = b; }
    { const int kap = c64 >> 4, hh = (c64 >> 3) & 1, jj = c64 & 7;
      G[base + CB_OFF + (size_t)((kap * 2 + hh) * F_ + f) * 8 + jj] = b; }
    float s = vb * vb;
    #pragma unroll
    for (int off = 1; off < 64; off <<= 1) s += __shfl_xor(s, off);
    __shared__ float part[2];
    if ((f & 63) == 0) part[f >> 6] = s;
    __syncthreads();
    if (f < 16) {
        const float csq = part[0] + part[1];
        const float chv = -0.5f * csq;
        const short vh = f2bf(chv);
        const short vl = f2bf(chv - bf2f(vh));
        const short val = (f == 0) ? vh : (f == 1) ? vl : (f == 2) ? (short)0x3F80 : (short)0;
        const int h2 = f >> 3, j2 = f & 7;
        G[base + (size_t)((16 + h2) * 64 + c64) * 8 + j2] = val;
    }
}

// Linear 34 KB chunk copy via async DMA (dst = wave-uniform base + lane*16).
__device__ __forceinline__ void stage_chunk(const short* __restrict__ G, short* dst,
                                            int ch, int wave, int lane) {
    const char* src = (const char*)(G + (size_t)ch * CH_SH);
    lch* d = (lch*)dst;
    #pragma unroll
    for (int t = 0; t < 8; ++t) {
        const int g = t * 256 + wave * 64 + lane;
        __builtin_amdgcn_global_load_lds((gch*)(src + (size_t)g * 16),
                                         d + (size_t)(t * 256 + wave * 64) * 16, 16, 0, 0);
    }
    if (wave < 2) {
        const int g = 2048 + wave * 64 + lane;
        __builtin_amdgcn_global_load_lds((gch*)(src + (size_t)g * 16),
                                         d + (size_t)(2048 + wave * 64) * 16, 16, 0, 0);
    }
}

__global__ __launch_bounds__(256, 2) void cluster_kernel(
        const float* __restrict__ x, const short* __restrict__ G,
        float* __restrict__ out) {
    __shared__ __align__(16) short SB[2][CH_SH];   // 2 x 34 KB, double-buffered
    const int tid = threadIdx.x;
    const int wave = tid >> 6, lane = tid & 63;
    const int h = lane >> 5, c32 = lane & 31;
    const int row0 = blockIdx.x * 128 + wave * 32;

    // ---- x prologue: issue ALL 16 loads first, then convert (one latency wave) ----
    const float4* xr4 = (const float4*)(x + (size_t)(row0 + c32) * F_);
    float4 xl[16];
    #pragma unroll
    for (int ks = 0; ks < 8; ++ks) {
        xl[2 * ks]     = xr4[ks * 4 + h * 2];
        xl[2 * ks + 1] = xr4[ks * 4 + h * 2 + 1];
    }
    v8s Bx[9];
    float xs = 0.f;
    #pragma unroll
    for (int ks = 0; ks < 8; ++ks) {
        float vv[8] = {xl[2*ks].x, xl[2*ks].y, xl[2*ks].z, xl[2*ks].w,
                       xl[2*ks+1].x, xl[2*ks+1].y, xl[2*ks+1].z, xl[2*ks+1].w};
        v8s fr;
        #pragma unroll
        for (int j = 0; j < 8; ++j) {
            short bb = f2bf(vv[j]);
            fr[j] = bb;
            float r = bf2f(bb);
            xs += r * r;        // ||x~||^2 of bf16-rounded values
        }
        Bx[ks] = fr;
    }
    xs += __shfl_xor(xs, 32);   // combine the two f-halves of this row
    {
        const float xh = -0.5f * xs;
        const short sxh = f2bf(xh);
        const short sxl = f2bf(xh - bf2f(sxh));
        v8s e = (v8s){0, 0, 0, 0, 0, 0, 0, 0};
        if (h == 0) { e[0] = (short)0x3F80; e[1] = (short)0x3F80; e[2] = sxh; e[3] = sxl; }
        Bx[8] = e;              // k=128,129: 1.0 (x csq limbs); 130,131: -xsq/2 limbs (x 1.0)
    }

    v16f Of[4];
    #pragma unroll
    for (int ft = 0; ft < 4; ++ft)
        #pragma unroll
        for (int e2 = 0; e2 < 16; ++e2) Of[ft][e2] = 0.f;
    float lden = 0.f;

    stage_chunk(G, SB[0], blockIdx.x & 7, wave, lane);
    asm volatile("s_waitcnt vmcnt(0)" ::: "memory");
    __syncthreads();

    #pragma unroll
    for (int i = 0; i < 8; ++i) {
        const short* CbS = SB[i & 1];
        const short* CTS = CbS + CB_OFF;
        if (i < 7) stage_chunk(G, SB[(i + 1) & 1], (i + 1 + blockIdx.x) & 7, wave, lane);

        // ---- stage 1: preload BOTH ct tiles' A-fragments, run 2 independent chains ----
        v8s af0[9], af1[9];
        #pragma unroll
        for (int ks = 0; ks < 9; ++ks) {
            af0[ks] = *(const v8s*)&CbS[(size_t)((ks * 2 + h) * 64 + c32) * 8];
            af1[ks] = *(const v8s*)&CbS[(size_t)((ks * 2 + h) * 64 + 32 + c32) * 8];
        }
        v16f a0, a1;
        #pragma unroll
        for (int e2 = 0; e2 < 16; ++e2) { a0[e2] = 0.f; a1[e2] = 0.f; }
        #pragma unroll
        for (int ks = 0; ks < 9; ++ks) {
            a0 = __builtin_amdgcn_mfma_f32_32x32x16_bf16(af0[ks], Bx[ks], a0, 0, 0, 0);
            a1 = __builtin_amdgcn_mfma_f32_32x32x16_bf16(af1[ks], Bx[ks], a1, 0, 0, 0);
        }

        // ---- preload ALL stage-2 B-fragments (hides ds latency behind exp chain) ----
        v8s cf[4][4];
        #pragma unroll
        for (int kap = 0; kap < 4; ++kap)
            #pragma unroll
            for (int ft = 0; ft < 4; ++ft)
                cf[kap][ft] = *(const v8s*)&CTS[(size_t)((kap * 2 + h) * F_ + ft * 32 + c32) * 8];

        // ---- epilogue + transpose + stage-2 per ct tile ----
        #pragma unroll
        for (int ct = 0; ct < 2; ++ct) {
            const v16f acc = ct ? a1 : a0;
            unsigned U[8];
            #pragma unroll
            for (int t = 0; t < 8; ++t) {
                const float d20 = fmaxf(-2.0f * acc[2 * t], 0.f);
                const float d21 = fmaxf(-2.0f * acc[2 * t + 1], 0.f);
                const float p0 = __expf(-__builtin_amdgcn_sqrtf(d20));
                const float p1 = __expf(-__builtin_amdgcn_sqrtf(d21));
                union { __hip_bfloat162 hh; unsigned u; } cv;
                cv.hh = __float22bfloat162_rn(make_float2(p0, p1));
                U[t] = cv.u;
                lden += __uint_as_float(cv.u << 16);        // denom from SAME rounded p
                lden += __uint_as_float(cv.u & 0xffff0000u);
            }
            #pragma unroll
            for (int kp = 0; kp < 2; ++kp) {
                unsigned s0 = U[4 * kp],     s2 = U[4 * kp + 2];
                unsigned s1 = U[4 * kp + 1], s3 = U[4 * kp + 3];
                pswap(s0, s2, lane);
                pswap(s1, s3, lane);
                union { v8s v; unsigned u[4]; } pf;
                pf.u[0] = s0; pf.u[1] = s1; pf.u[2] = s2; pf.u[3] = s3;
                const int kap = ct * 2 + kp;
                #pragma unroll
                for (int ft = 0; ft < 4; ++ft)
                    Of[ft] = __builtin_amdgcn_mfma_f32_32x32x16_bf16(pf.v, cf[kap][ft], Of[ft], 0, 0, 0);
            }
        }
        asm volatile("s_waitcnt vmcnt(0)" ::: "memory");
        __syncthreads();
    }

    // Denominator: per-lane sum covers all 512 clusters of row c32 (both halves).
    lden += __shfl_xor(lden, 32);
    const float inv = 1.0f / lden;
    float invr[16];
    #pragma unroll
    for (int r = 0; r < 16; ++r)
        invr[r] = __shfl(inv, (r & 3) + 8 * (r >> 2) + 4 * h);
    // Stage-2 D: row = (r&3)+8*(r>>2)+4h (x-row), col = c32 (feature within f-tile).
    #pragma unroll
    for (int ft = 0; ft < 4; ++ft)
        #pragma unroll
        for (int r = 0; r < 16; ++r) {
            const int xrow = (r & 3) + 8 * (r >> 2) + 4 * h;
            out[(size_t)(row0 + xrow) * F_ + ft * 32 + c32] = Of[ft][r] * invr[r];
        }
}

extern "C" void kernel_launch(void* const* d_in, const int* in_sizes, int n_in,
                              void* d_out, int out_size, void* d_ws, size_t ws_size,
                              hipStream_t stream) {
    const float* x       = (const float*)d_in[0];   // [8,8192,128] fp32
    const float* centers = (const float*)d_in[1];   // [512,128] fp32
    float* out = (float*)d_out;                     // [8,8192,128] fp32
    short* G = (short*)d_ws;                        // 8 chunks x 34816 B = 278528 B
    prep_kernel<<<K_, F_, 0, stream>>>(centers, G);
    cluster_kernel<<<M_ / 128, 256, 0, stream>>>(x, G, out);
}

// Round 6
// 103.588 us; speedup vs baseline: 1.4086x; 1.4086x over previous
//
#include <hip/hip_runtime.h>
#include <hip/hip_bf16.h>

typedef short v8s __attribute__((ext_vector_type(8)));
typedef float v16f __attribute__((ext_vector_type(16)));
typedef unsigned v2u __attribute__((ext_vector_type(2)));

#define F_ 128
#define K_ 512
#define M_ 65536
#define CH_SH 17408   // shorts per chunk table: Cb' 9216 (64c x 144f) + CT' 8192 (64c x 128f)
#define CB_OFF 9216

typedef __attribute__((address_space(1))) const char gch;
typedef __attribute__((address_space(3))) char lch;

__device__ __forceinline__ short f2bf(float f) {
    union { float f; unsigned u; } v; v.f = f;
    unsigned u = v.u;
    u = (u + 0x7FFFu + ((u >> 16) & 1u)) >> 16;  // RNE
    return (short)u;
}
__device__ __forceinline__ float bf2f(short s) {
    union { float f; unsigned u; } v;
    v.u = ((unsigned)(unsigned short)s) << 16;
    return v.f;
}

#if __has_builtin(__builtin_amdgcn_permlane32_swap)
#define HAVE_PLS 1
#endif

// (a,b) -> (a.lo||b.lo, a.hi||b.hi): the half-wave exchange for C->A layout.
__device__ __forceinline__ void pswap(unsigned &a, unsigned &b, int lane) {
#ifdef HAVE_PLS
    v2u r = __builtin_amdgcn_permlane32_swap(a, b, false, false);
    a = (unsigned)r.x; b = (unsigned)r.y;
#else
    unsigned sa = (unsigned)__shfl_xor((int)a, 32);
    unsigned sb = (unsigned)__shfl_xor((int)b, 32);
    if (lane & 32) a = sb; else b = sa;
#endif
}

// Build combined per-chunk tables in fragment-granule order (verified R4).
__global__ void prep_kernel(const float* __restrict__ centers, short* __restrict__ G) {
    const int c = blockIdx.x;     // 512 clusters
    const int f = threadIdx.x;    // 128 features
    const int ch = c >> 6, c64 = c & 63;
    const size_t base = (size_t)ch * CH_SH;
    float v = centers[c * F_ + f];
    short b = f2bf(v);
    float vb = bf2f(b);
    { const int ks = f >> 4, h = (f >> 3) & 1, j = f & 7;
      G[base + (size_t)((ks * 2 + h) * 64 + c64) * 8 + j] = b; }
    { const int kap = c64 >> 4, hh = (c64 >> 3) & 1, jj = c64 & 7;
      G[base + CB_OFF + (size_t)((kap * 2 + hh) * F_ + f) * 8 + jj] = b; }
    float s = vb * vb;
    #pragma unroll
    for (int off = 1; off < 64; off <<= 1) s += __shfl_xor(s, off);
    __shared__ float part[2];
    if ((f & 63) == 0) part[f >> 6] = s;
    __syncthreads();
    if (f < 16) {
        const float csq = part[0] + part[1];
        const float chv = -0.5f * csq;
        const short vh = f2bf(chv);
        const short vl = f2bf(chv - bf2f(vh));
        const short val = (f == 0) ? vh : (f == 1) ? vl : (f == 2) ? (short)0x3F80 : (short)0;
        const int h2 = f >> 3, j2 = f & 7;
        G[base + (size_t)((16 + h2) * 64 + c64) * 8 + j2] = val;
    }
}

// Linear 34 KB chunk copy via async DMA (dst = wave-uniform base + lane*16).
__device__ __forceinline__ void stage_chunk(const short* __restrict__ G, short* dst,
                                            int ch, int wave, int lane) {
    const char* src = (const char*)(G + (size_t)ch * CH_SH);
    lch* d = (lch*)dst;
    #pragma unroll
    for (int t = 0; t < 8; ++t) {
        const int g = t * 256 + wave * 64 + lane;
        __builtin_amdgcn_global_load_lds((gch*)(src + (size_t)g * 16),
                                         d + (size_t)(t * 256 + wave * 64) * 16, 16, 0, 0);
    }
    if (wave < 2) {
        const int g = 2048 + wave * 64 + lane;
        __builtin_amdgcn_global_load_lds((gch*)(src + (size_t)g * 16),
                                         d + (size_t)(2048 + wave * 64) * 16, 16, 0, 0);
    }
}

__global__ __launch_bounds__(256, 2) void cluster_kernel(
        const float* __restrict__ x, const short* __restrict__ G,
        float* __restrict__ out) {
    __shared__ __align__(16) short SB[2][CH_SH];   // 2 x 34 KB, double-buffered
    const int tid = threadIdx.x;
    const int wave = tid >> 6, lane = tid & 63;
    const int h = lane >> 5, c32 = lane & 31;
    const int row0 = blockIdx.x * 128 + wave * 32;

    // ---- x prologue: issue ALL 16 loads first, then convert (one latency wave) ----
    const float4* xr4 = (const float4*)(x + (size_t)(row0 + c32) * F_);
    float4 xl[16];
    #pragma unroll
    for (int ks = 0; ks < 8; ++ks) {
        xl[2 * ks]     = xr4[ks * 4 + h * 2];
        xl[2 * ks + 1] = xr4[ks * 4 + h * 2 + 1];
    }
    v8s Bx[9];
    float xs = 0.f;
    #pragma unroll
    for (int ks = 0; ks < 8; ++ks) {
        float vv[8] = {xl[2*ks].x, xl[2*ks].y, xl[2*ks].z, xl[2*ks].w,
                       xl[2*ks+1].x, xl[2*ks+1].y, xl[2*ks+1].z, xl[2*ks+1].w};
        v8s fr;
        #pragma unroll
        for (int j = 0; j < 8; ++j) {
            short bb = f2bf(vv[j]);
            fr[j] = bb;
            float r = bf2f(bb);
            xs += r * r;        // ||x~||^2 of bf16-rounded values
        }
        Bx[ks] = fr;
    }
    xs += __shfl_xor(xs, 32);   // combine the two f-halves of this row
    {
        const float xh = -0.5f * xs;
        const short sxh = f2bf(xh);
        const short sxl = f2bf(xh - bf2f(sxh));
        v8s e = (v8s){0, 0, 0, 0, 0, 0, 0, 0};
        if (h == 0) { e[0] = (short)0x3F80; e[1] = (short)0x3F80; e[2] = sxh; e[3] = sxl; }
        Bx[8] = e;              // k=128,129: 1.0 (x csq limbs); 130,131: -xsq/2 limbs (x 1.0)
    }

    v16f Of[4];
    #pragma unroll
    for (int ft = 0; ft < 4; ++ft)
        #pragma unroll
        for (int e2 = 0; e2 < 16; ++e2) Of[ft][e2] = 0.f;
    float lden = 0.f;

    stage_chunk(G, SB[0], blockIdx.x & 7, wave, lane);
    asm volatile("s_waitcnt vmcnt(0)" ::: "memory");
    __syncthreads();

    #pragma unroll 2
    for (int i = 0; i < 8; ++i) {
        const short* CbS = SB[i & 1];
        const short* CTS = CbS + CB_OFF;
        if (i < 7) stage_chunk(G, SB[(i + 1) & 1], (i + 1 + blockIdx.x) & 7, wave, lane);

        // ---- stage 1: two independent chains, sliding 2-deep A-frag window ----
        v16f a0, a1;
        #pragma unroll
        for (int e2 = 0; e2 < 16; ++e2) { a0[e2] = 0.f; a1[e2] = 0.f; }
        {
            v8s f0a = *(const v8s*)&CbS[(size_t)((0 * 2 + h) * 64 + c32) * 8];
            v8s f1a = *(const v8s*)&CbS[(size_t)((0 * 2 + h) * 64 + 32 + c32) * 8];
            v8s f0b = *(const v8s*)&CbS[(size_t)((1 * 2 + h) * 64 + c32) * 8];
            v8s f1b = *(const v8s*)&CbS[(size_t)((1 * 2 + h) * 64 + 32 + c32) * 8];
            #pragma unroll
            for (int ks = 0; ks < 9; ++ks) {
                v8s c0 = f0a, c1 = f1a;
                f0a = f0b; f1a = f1b;
                if (ks < 7) {
                    f0b = *(const v8s*)&CbS[(size_t)(((ks + 2) * 2 + h) * 64 + c32) * 8];
                    f1b = *(const v8s*)&CbS[(size_t)(((ks + 2) * 2 + h) * 64 + 32 + c32) * 8];
                }
                a0 = __builtin_amdgcn_mfma_f32_32x32x16_bf16(c0, Bx[ks], a0, 0, 0, 0);
                a1 = __builtin_amdgcn_mfma_f32_32x32x16_bf16(c1, Bx[ks], a1, 0, 0, 0);
            }
        }

        // ---- per ct tile: cf prefetch (hidden under exp chain) + epilogue + stage-2 ----
        #pragma unroll
        for (int ct = 0; ct < 2; ++ct) {
            v8s cf[8];
            #pragma unroll
            for (int kp = 0; kp < 2; ++kp)
                #pragma unroll
                for (int ft = 0; ft < 4; ++ft)
                    cf[kp * 4 + ft] = *(const v8s*)
                        &CTS[(size_t)(((ct * 2 + kp) * 2 + h) * F_ + ft * 32 + c32) * 8];
            const v16f acc = ct ? a1 : a0;
            unsigned U[8];
            #pragma unroll
            for (int t = 0; t < 8; ++t) {
                const float d20 = fmaxf(-2.0f * acc[2 * t], 0.f);
                const float d21 = fmaxf(-2.0f * acc[2 * t + 1], 0.f);
                const float p0 = __expf(-__builtin_amdgcn_sqrtf(d20));
                const float p1 = __expf(-__builtin_amdgcn_sqrtf(d21));
                union { __hip_bfloat162 hh; unsigned u; } cv;
                cv.hh = __float22bfloat162_rn(make_float2(p0, p1));
                U[t] = cv.u;
                lden += __uint_as_float(cv.u << 16);        // denom from SAME rounded p
                lden += __uint_as_float(cv.u & 0xffff0000u);
            }
            #pragma unroll
            for (int kp = 0; kp < 2; ++kp) {
                unsigned s0 = U[4 * kp],     s2 = U[4 * kp + 2];
                unsigned s1 = U[4 * kp + 1], s3 = U[4 * kp + 3];
                pswap(s0, s2, lane);
                pswap(s1, s3, lane);
                union { v8s v; unsigned u[4]; } pf;
                pf.u[0] = s0; pf.u[1] = s1; pf.u[2] = s2; pf.u[3] = s3;
                #pragma unroll
                for (int ft = 0; ft < 4; ++ft)
                    Of[ft] = __builtin_amdgcn_mfma_f32_32x32x16_bf16(pf.v, cf[kp * 4 + ft], Of[ft], 0, 0, 0);
            }
        }
        asm volatile("s_waitcnt vmcnt(0)" ::: "memory");
        __syncthreads();
    }

    // Denominator: per-lane sum covers all 512 clusters of row c32 (both halves).
    lden += __shfl_xor(lden, 32);
    const float inv = 1.0f / lden;
    float invr[16];
    #pragma unroll
    for (int r = 0; r < 16; ++r)
        invr[r] = __shfl(inv, (r & 3) + 8 * (r >> 2) + 4 * h);
    // Stage-2 D: row = (r&3)+8*(r>>2)+4h (x-row), col = c32 (feature within f-tile).
    #pragma unroll
    for (int ft = 0; ft < 4; ++ft)
        #pragma unroll
        for (int r = 0; r < 16; ++r) {
            const int xrow = (r & 3) + 8 * (r >> 2) + 4 * h;
            out[(size_t)(row0 + xrow) * F_ + ft * 32 + c32] = Of[ft][r] * invr[r];
        }
}

extern "C" void kernel_launch(void* const* d_in, const int* in_sizes, int n_in,
                              void* d_out, int out_size, void* d_ws, size_t ws_size,
                              hipStream_t stream) {
    const float* x       = (const float*)d_in[0];   // [8,8192,128] fp32
    const float* centers = (const float*)d_in[1];   // [512,128] fp32
    float* out = (float*)d_out;                     // [8,8192,128] fp32
    short* G = (short*)d_ws;                        // 8 chunks x 34816 B = 278528 B
    prep_kernel<<<K_, F_, 0, stream>>>(centers, G);
    cluster_kernel<<<M_ / 128, 256, 0, stream>>>(x, G, out);
}